// Round 1
// baseline (570.544 us; speedup 1.0000x reference)
//
#include <hip/hip_runtime.h>

// PendulumSolver: B=65536 independent driven pendulums, RK4, 999 steps.
// out[b*1000 + t] = theta_b(t), fp32.
// Round 1: correctness-first. Precise sinf/cosf, reference op-order mirrored.
// 1 thread = 1 pendulum. float4-batched output stores (aligned: 1000*4B rows,
// 4000 % 16 == 0).

#define NSTEP 999

__global__ __launch_bounds__(256) void pend_kernel(
    const float* __restrict__ init,    // (B,2) theta, thdot
    const float* __restrict__ params,  // (B,4) omega, gamma, A, phi
    float* __restrict__ out,           // (B,1000)
    int B)
{
    int b = blockIdx.x * blockDim.x + threadIdx.x;
    if (b >= B) return;

    float th = init[2 * b + 0];
    float w  = init[2 * b + 1];
    const float omega = params[4 * b + 0];
    const float gamma = params[4 * b + 1];
    const float A     = params[4 * b + 2];
    const float phi   = params[4 * b + 3];

    const float dt  = 0.01f;          // fp32(0.01), matches jnp.float32(DT)
    const float hdt = 0.5f * dt;      // exact
    const float dt6 = dt / 6.0f;      // fp32 divide, matches dt/6.0 in fp32
    const float om2 = omega * omega;                 // (omega*omega)
    const float Fco = (A * omega) * omega;           // ((A*omega)*omega) - ref order
    const float tp  = 6.28318530717958647692f * phi; // (fp32(2*pi)) * phi

    float4* out4 = (float4*)(out + (size_t)b * 1000);

    // One RK4 step at time index k (t = k*dt). Updates th, w; returns new th.
    auto step = [&](int k) -> float {
        float t  = (float)k * dt;
        float c1 = cosf(tp * t);
        float c2 = cosf(tp * (t + hdt));   // stages 2 and 3 share this time
        float c4 = cosf(tp * (t + dt));

        // stage 1: k1 = f(t, y)
        float a1  = Fco * c1 - gamma * w - om2 * sinf(th);
        // stage 2: k2 = f(t+h/2, y + h/2*k1)
        float th2 = th + hdt * w;
        float w2_ = w  + hdt * a1;
        float a2  = Fco * c2 - gamma * w2_ - om2 * sinf(th2);
        // stage 3: k3 = f(t+h/2, y + h/2*k2)
        float th3 = th + hdt * w2_;
        float w3_ = w  + hdt * a2;
        float a3  = Fco * c2 - gamma * w3_ - om2 * sinf(th3);
        // stage 4: k4 = f(t+h, y + h*k3)
        float th4 = th + dt * w3_;
        float w4_ = w  + dt * a3;
        float a4  = Fco * c4 - gamma * w4_ - om2 * sinf(th4);

        // y += dt/6 * (k1 + 2*k2 + 2*k3 + k4), left-to-right like the ref
        float ks_th = w  + 2.0f * w2_ + 2.0f * w3_ + w4_;
        float ks_w  = a1 + 2.0f * a2  + 2.0f * a3  + a4;
        th = th + dt6 * ks_th;
        w  = w  + dt6 * ks_w;
        return th;
    };

    // positions 0..999; pos 0 = initial theta, pos k+1 = theta after step k.
    float4 ob;
    ob.x = th;
    ob.y = step(0);
    ob.z = step(1);
    ob.w = step(2);
    out4[0] = ob;

    for (int c = 1; c < 250; ++c) {
        int k0 = 4 * c - 1;
        ob.x = step(k0);
        ob.y = step(k0 + 1);
        ob.z = step(k0 + 2);
        ob.w = step(k0 + 3);
        out4[c] = ob;
    }
}

extern "C" void kernel_launch(void* const* d_in, const int* in_sizes, int n_in,
                              void* d_out, int out_size, void* d_ws, size_t ws_size,
                              hipStream_t stream) {
    const float* init   = (const float*)d_in[0];
    const float* params = (const float*)d_in[1];
    float* out = (float*)d_out;
    int B = in_sizes[0] / 2;

    int block = 256;
    int grid  = (B + block - 1) / block;
    hipLaunchKernelGGL(pend_kernel, dim3(grid), dim3(block), 0, stream,
                       init, params, out, B);
}

// Round 2
// 338.581 us; speedup vs baseline: 1.6851x; 1.6851x over previous
//
#include <hip/hip_runtime.h>

// PendulumSolver: B=65536 independent driven pendulums, RK4, 999 steps.
// out[b*1000 + t] = theta_b(t), fp32.
// Round 2: replace libm sinf/cosf with custom ~1-ulp quadrant-reduced trig.
//   - magic-number rint (+1.5*2^23 trick), quadrant bits from mantissa
//   - FMA-based Cody-Waite pi/2 reduction (2 terms; product exact inside FMA;
//     residual ~1e-13 rad for |n|<=64 — args here are |x| < ~64 rad)
//   - cephes degree-7 sin / degree-6 cos minimax polys on [-pi/4, pi/4]
//   - branchless quadrant select (cndmask) + sign-bit XOR
// RK4 op order / argument values identical to round 1.
// 1 thread = 1 pendulum; occupancy is capped at 1 wave/SIMD (B=65536), so the
// win comes from shortening the serial dependency chain.

__device__ __forceinline__ float sincos_core(float x, int qoff) {
    const float TWO_OVER_PI = 0.6366197723675814f;
    const float MAGIC = 12582912.0f;                 // 1.5 * 2^23
    float nb = fmaf(x, TWO_OVER_PI, MAGIC);          // round-to-nearest-even
    int   q  = __float_as_int(nb);                   // low mantissa bits = n (mod 2^22)
    float n  = nb - MAGIC;                           // exact float n
    // Cody-Waite: r = x - n*pi/2, products exact inside FMA
    const float P1 = 1.57079637050628662109375f;     // fp32(pi/2)
    const float P2 = -4.37113900018624283e-8f;       // pi/2 - P1 (fp32)
    float r = fmaf(n, -P1, x);
    r = fmaf(n, -P2, r);
    float r2 = r * r;
    // sin poly on [-pi/4, pi/4] (cephes): r + r^3*(S1 + r2*(S2 + r2*S3))
    float ps = fmaf(r2, -1.9515295891e-4f, 8.3321608736e-3f);
    ps = fmaf(ps, r2, -1.6666654611e-1f);
    float sr = fmaf(ps * r2, r, r);
    // cos poly: 1 - r2/2 + r4*(C1 + r2*(C2 + r2*C3))
    float pc = fmaf(r2, 2.443315711809948e-5f, -1.388731625493765e-3f);
    pc = fmaf(pc, r2, 4.166664568298827e-2f);
    float cr = fmaf(pc, r2 * r2, fmaf(r2, -0.5f, 1.0f));
    q += qoff;
    float v = (q & 1) ? cr : sr;
    unsigned s = ((unsigned)(q & 2)) << 30;          // sign flip if q & 2
    return __int_as_float(__float_as_int(v) ^ (int)s);
}

__device__ __forceinline__ float fast_sin(float x) { return sincos_core(x, 0); }
__device__ __forceinline__ float fast_cos(float x) { return sincos_core(x, 1); }

__global__ __launch_bounds__(256) void pend_kernel(
    const float* __restrict__ init,    // (B,2) theta, thdot
    const float* __restrict__ params,  // (B,4) omega, gamma, A, phi
    float* __restrict__ out,           // (B,1000)
    int B)
{
    int b = blockIdx.x * blockDim.x + threadIdx.x;
    if (b >= B) return;

    float th = init[2 * b + 0];
    float w  = init[2 * b + 1];
    const float omega = params[4 * b + 0];
    const float gamma = params[4 * b + 1];
    const float A     = params[4 * b + 2];
    const float phi   = params[4 * b + 3];

    const float dt  = 0.01f;
    const float hdt = 0.5f * dt;
    const float dt6 = dt / 6.0f;
    const float om2 = omega * omega;
    const float Fco = (A * omega) * omega;
    const float tp  = 6.28318530717958647692f * phi;

    float4* out4 = (float4*)(out + (size_t)b * 1000);

    auto step = [&](int k) -> float {
        float t  = (float)k * dt;
        float c1 = fast_cos(tp * t);
        float c2 = fast_cos(tp * (t + hdt));   // stages 2 and 3 share this time
        float c4 = fast_cos(tp * (t + dt));

        float a1  = Fco * c1 - gamma * w - om2 * fast_sin(th);
        float th2 = th + hdt * w;
        float w2_ = w  + hdt * a1;
        float a2  = Fco * c2 - gamma * w2_ - om2 * fast_sin(th2);
        float th3 = th + hdt * w2_;
        float w3_ = w  + hdt * a2;
        float a3  = Fco * c2 - gamma * w3_ - om2 * fast_sin(th3);
        float th4 = th + dt * w3_;
        float w4_ = w  + dt * a3;
        float a4  = Fco * c4 - gamma * w4_ - om2 * fast_sin(th4);

        float ks_th = w  + 2.0f * w2_ + 2.0f * w3_ + w4_;
        float ks_w  = a1 + 2.0f * a2  + 2.0f * a3  + a4;
        th = th + dt6 * ks_th;
        w  = w  + dt6 * ks_w;
        return th;
    };

    float4 ob;
    ob.x = th;
    ob.y = step(0);
    ob.z = step(1);
    ob.w = step(2);
    out4[0] = ob;

    for (int c = 1; c < 250; ++c) {
        int k0 = 4 * c - 1;
        ob.x = step(k0);
        ob.y = step(k0 + 1);
        ob.z = step(k0 + 2);
        ob.w = step(k0 + 3);
        out4[c] = ob;
    }
}

extern "C" void kernel_launch(void* const* d_in, const int* in_sizes, int n_in,
                              void* d_out, int out_size, void* d_ws, size_t ws_size,
                              hipStream_t stream) {
    const float* init   = (const float*)d_in[0];
    const float* params = (const float*)d_in[1];
    float* out = (float*)d_out;
    int B = in_sizes[0] / 2;

    int block = 256;
    int grid  = (B + block - 1) / block;
    hipLaunchKernelGGL(pend_kernel, dim3(grid), dim3(block), 0, stream,
                       init, params, out, B);
}

// Round 3
// 273.607 us; speedup vs baseline: 2.0853x; 1.2375x over previous
//
#include <hip/hip_runtime.h>

// PendulumSolver: B=65536 independent driven pendulums, RK4, 999 steps.
// Round 3: cut per-step trig from 7 full evals to 3 cos + 1 sincos + 3 cheap
// small-angle reconstructions.
//   - forcing cos (x3): Cody-Waite core, BIT-IDENTICAL to round 2 (passed).
//   - sin(th): shared-reduction sincos, sin path bit-identical to round 2.
//   - sin(th2/3/4): sin(th+d) = sin(th)cos(d)+cos(th)sin(d), d = fl(th+eps)-th
//     (Sterbenz-exact delta -> argument matches reference's rounded stage
//     angle bit-exactly even for |th|~250). Polys to d^5/d^6: <3 ulp at d=0.25.
// Perturbation class unchanged (1-2 ulp, identical args) -> absmax should hold.

__device__ __forceinline__ float fast_cos(float x) {
    const float TWO_OVER_PI = 0.6366197723675814f;
    const float MAGIC = 12582912.0f;                 // 1.5 * 2^23
    float nb = fmaf(x, TWO_OVER_PI, MAGIC);
    int   q  = __float_as_int(nb);
    float n  = nb - MAGIC;
    const float P1 = 1.57079637050628662109375f;
    const float P2 = -4.37113900018624283e-8f;
    float r = fmaf(n, -P1, x);
    r = fmaf(n, -P2, r);
    float r2 = r * r;
    float ps = fmaf(r2, -1.9515295891e-4f, 8.3321608736e-3f);
    ps = fmaf(ps, r2, -1.6666654611e-1f);
    float sr = fmaf(ps * r2, r, r);
    float pc = fmaf(r2, 2.443315711809948e-5f, -1.388731625493765e-3f);
    pc = fmaf(pc, r2, 4.166664568298827e-2f);
    float cr = fmaf(pc, r2 * r2, fmaf(r2, -0.5f, 1.0f));
    q += 1;                                          // cos(x) = sin(x + pi/2)
    float v = (q & 1) ? cr : sr;
    unsigned s = ((unsigned)(q & 2)) << 30;
    return __int_as_float(__float_as_int(v) ^ (int)s);
}

__device__ __forceinline__ void fast_sincos(float x, float& so, float& co) {
    const float TWO_OVER_PI = 0.6366197723675814f;
    const float MAGIC = 12582912.0f;
    float nb = fmaf(x, TWO_OVER_PI, MAGIC);
    int   q  = __float_as_int(nb);
    float n  = nb - MAGIC;
    const float P1 = 1.57079637050628662109375f;
    const float P2 = -4.37113900018624283e-8f;
    float r = fmaf(n, -P1, x);
    r = fmaf(n, -P2, r);
    float r2 = r * r;
    float ps = fmaf(r2, -1.9515295891e-4f, 8.3321608736e-3f);
    ps = fmaf(ps, r2, -1.6666654611e-1f);
    float sr = fmaf(ps * r2, r, r);
    float pc = fmaf(r2, 2.443315711809948e-5f, -1.388731625493765e-3f);
    pc = fmaf(pc, r2, 4.166664568298827e-2f);
    float cr = fmaf(pc, r2 * r2, fmaf(r2, -0.5f, 1.0f));
    bool odd = (q & 1) != 0;
    float vs = odd ? cr : sr;
    float vc = odd ? sr : cr;
    unsigned ss = ((unsigned)(q & 2)) << 30;
    unsigned sc = ((unsigned)((q + 1) & 2)) << 30;
    so = __int_as_float(__float_as_int(vs) ^ (int)ss);
    co = __int_as_float(__float_as_int(vc) ^ (int)sc);
}

// sin(th + d) from (sin th, cos th); |d| <= ~0.3
__device__ __forceinline__ float sin_near(float sth, float cth, float d) {
    float d2 = d * d;
    float sd = d * fmaf(d2, fmaf(d2, 8.33333333e-3f, -1.66666667e-1f), 1.0f);
    float cd = fmaf(fmaf(fmaf(d2, -1.38888889e-3f, 4.16666667e-2f), d2, -0.5f),
                    d2, 1.0f);
    return fmaf(sth, cd, cth * sd);
}

__global__ __launch_bounds__(256) void pend_kernel(
    const float* __restrict__ init,    // (B,2) theta, thdot
    const float* __restrict__ params,  // (B,4) omega, gamma, A, phi
    float* __restrict__ out,           // (B,1000)
    int B)
{
    int b = blockIdx.x * blockDim.x + threadIdx.x;
    if (b >= B) return;

    float th = init[2 * b + 0];
    float w  = init[2 * b + 1];
    const float omega = params[4 * b + 0];
    const float gamma = params[4 * b + 1];
    const float A     = params[4 * b + 2];
    const float phi   = params[4 * b + 3];

    const float dt  = 0.01f;
    const float hdt = 0.5f * dt;
    const float dt6 = dt / 6.0f;
    const float om2 = omega * omega;
    const float Fco = (A * omega) * omega;
    const float tp  = 6.28318530717958647692f * phi;

    float4* out4 = (float4*)(out + (size_t)b * 1000);

    auto step = [&](int k) -> float {
        float t  = (float)k * dt;
        float c1 = fast_cos(tp * t);
        float c2 = fast_cos(tp * (t + hdt));   // stages 2 and 3 share this time
        float c4 = fast_cos(tp * (t + dt));

        float sth, cth;
        fast_sincos(th, sth, cth);

        float a1  = Fco * c1 - gamma * w - om2 * sth;
        float th2 = th + hdt * w;              // available at step start
        float s2  = sin_near(sth, cth, th2 - th);
        float w2_ = w + hdt * a1;
        float a2  = Fco * c2 - gamma * w2_ - om2 * s2;
        float th3 = th + hdt * w2_;
        float s3  = sin_near(sth, cth, th3 - th);
        float w3_ = w + hdt * a2;
        float a3  = Fco * c2 - gamma * w3_ - om2 * s3;
        float th4 = th + dt * w3_;
        float s4  = sin_near(sth, cth, th4 - th);
        float w4_ = w + dt * a3;
        float a4  = Fco * c4 - gamma * w4_ - om2 * s4;

        float ks_th = w  + 2.0f * w2_ + 2.0f * w3_ + w4_;
        float ks_w  = a1 + 2.0f * a2  + 2.0f * a3  + a4;
        th = th + dt6 * ks_th;
        w  = w + dt6 * ks_w;
        return th;
    };

    float4 ob;
    ob.x = th;
    ob.y = step(0);
    ob.z = step(1);
    ob.w = step(2);
    out4[0] = ob;

    for (int c = 1; c < 250; ++c) {
        int k0 = 4 * c - 1;
        ob.x = step(k0);
        ob.y = step(k0 + 1);
        ob.z = step(k0 + 2);
        ob.w = step(k0 + 3);
        out4[c] = ob;
    }
}

extern "C" void kernel_launch(void* const* d_in, const int* in_sizes, int n_in,
                              void* d_out, int out_size, void* d_ws, size_t ws_size,
                              hipStream_t stream) {
    const float* init   = (const float*)d_in[0];
    const float* params = (const float*)d_in[1];
    float* out = (float*)d_out;
    int B = in_sizes[0] / 2;

    int block = 256;
    int grid  = (B + block - 1) / block;
    hipLaunchKernelGGL(pend_kernel, dim3(grid), dim3(block), 0, stream,
                       init, params, out, B);
}

// Round 4
// 204.769 us; speedup vs baseline: 2.7863x; 1.3362x over previous
//
#include <hip/hip_runtime.h>

// PendulumSolver: B=65536 independent driven pendulums, RK4, 999 steps.
// Round 4: issue-bound (VALUBusy 84.5% @ 1 wave/SIMD) -> cut instruction count.
//  1) Forcing cos: 1 packed sincos(y1) + small-angle recon for y2=y1+e2,
//     y3=y1+e3 (|e| <= tp*dt <= 0.063; e from fp32 subtract, arg error <= ulp(e)
//     -> evaluation-class). Args remain bit-identical to rounds 1-3.
//  2) Packed fp32 via ext_vector_type(2) + __builtin_elementwise_fma
//     -> v_pk_fma_f32: pack sincos(th) with sincos(y1); pack the two
//     small-angle poly pairs (s2,c2) and (s3,c4). s4 recon stays scalar.
// Dynamics / update expressions identical source form to rounds 1-3 (passed,
// absmax 0.0625 across all three -> systematic fp32 floor, trig noise below it).

typedef float v2f __attribute__((ext_vector_type(2)));

__device__ __forceinline__ v2f vfma(v2f a, v2f b, v2f c) {
#if __has_builtin(__builtin_elementwise_fma)
    return __builtin_elementwise_fma(a, b, c);
#else
    v2f r; r.x = fmaf(a.x, b.x, c.x); r.y = fmaf(a.y, b.y, c.y); return r;
#endif
}

__device__ __forceinline__ v2f splat(float v) { v2f r; r.x = v; r.y = v; return r; }

// Packed 2-lane sincos, lane-exact match of round-3's fast_sincos/fast_cos.
__device__ __forceinline__ void sincos2(float xa, float xb,
                                        float& sa, float& ca,
                                        float& sb, float& cb)
{
    v2f x; x.x = xa; x.y = xb;
    v2f nb = vfma(x, splat(0.6366197723675814f), splat(12582912.0f));
    int qa = __float_as_int(nb.x);
    int qb = __float_as_int(nb.y);
    v2f n = nb - splat(12582912.0f);
    v2f r = vfma(n, splat(-1.57079637050628662109375f), x);
    r = vfma(n, splat(4.37113900018624283e-8f), r);        // == fmaf(n,-P2,r) of R3
    v2f r2 = r * r;
    v2f ps = vfma(r2, splat(-1.9515295891e-4f), splat(8.3321608736e-3f));
    ps = vfma(ps, r2, splat(-1.6666654611e-1f));
    v2f sr = vfma(ps * r2, r, r);
    v2f pc = vfma(r2, splat(2.443315711809948e-5f), splat(-1.388731625493765e-3f));
    pc = vfma(pc, r2, splat(4.166664568298827e-2f));
    v2f cr = vfma(pc, r2 * r2, vfma(r2, splat(-0.5f), splat(1.0f)));

    bool oa = (qa & 1) != 0;
    float vsa = oa ? cr.x : sr.x;
    float vca = oa ? sr.x : cr.x;
    unsigned ssa = ((unsigned)(qa & 2)) << 30;
    unsigned sca = ((unsigned)((qa + 1) & 2)) << 30;
    sa = __int_as_float(__float_as_int(vsa) ^ (int)ssa);
    ca = __int_as_float(__float_as_int(vca) ^ (int)sca);

    bool ob = (qb & 1) != 0;
    float vsb = ob ? cr.y : sr.y;
    float vcb = ob ? sr.y : cr.y;
    unsigned ssb = ((unsigned)(qb & 2)) << 30;
    unsigned scb = ((unsigned)((qb + 1) & 2)) << 30;
    sb = __int_as_float(__float_as_int(vsb) ^ (int)ssb);
    cb = __int_as_float(__float_as_int(vcb) ^ (int)scb);
}

// Packed small-angle sin/cos of (da, db); |d| <= ~0.3. Same coeffs as R3.
__device__ __forceinline__ void near2(float da, float db, v2f& sd, v2f& cd) {
    v2f d; d.x = da; d.y = db;
    v2f d2 = d * d;
    sd = d * vfma(d2, vfma(d2, splat(8.33333333e-3f), splat(-1.66666667e-1f)),
                  splat(1.0f));
    cd = vfma(vfma(vfma(d2, splat(-1.38888889e-3f), splat(4.16666667e-2f)),
                   d2, splat(-0.5f)),
              d2, splat(1.0f));
}

// Scalar small-angle sin(th + d), same as round 3.
__device__ __forceinline__ float sin_near(float sth, float cth, float d) {
    float d2 = d * d;
    float sdv = d * fmaf(d2, fmaf(d2, 8.33333333e-3f, -1.66666667e-1f), 1.0f);
    float cdv = fmaf(fmaf(fmaf(d2, -1.38888889e-3f, 4.16666667e-2f), d2, -0.5f),
                     d2, 1.0f);
    return fmaf(sth, cdv, cth * sdv);
}

__global__ __launch_bounds__(256) void pend_kernel(
    const float* __restrict__ init,    // (B,2) theta, thdot
    const float* __restrict__ params,  // (B,4) omega, gamma, A, phi
    float* __restrict__ out,           // (B,1000)
    int B)
{
    int b = blockIdx.x * blockDim.x + threadIdx.x;
    if (b >= B) return;

    float th = init[2 * b + 0];
    float w  = init[2 * b + 1];
    const float omega = params[4 * b + 0];
    const float gamma = params[4 * b + 1];
    const float A     = params[4 * b + 2];
    const float phi   = params[4 * b + 3];

    const float dt  = 0.01f;
    const float hdt = 0.5f * dt;
    const float dt6 = dt / 6.0f;
    const float om2 = omega * omega;
    const float Fco = (A * omega) * omega;
    const float tp  = 6.28318530717958647692f * phi;

    float4* out4 = (float4*)(out + (size_t)b * 1000);

    auto step = [&](int k) -> float {
        float t  = (float)k * dt;
        float y1 = tp * t;
        float y2 = tp * (t + hdt);      // bit-identical arg to R3's c2
        float y3 = tp * (t + dt);       // bit-identical arg to R3's c4
        float e2 = y2 - y1;             // |e2| <= tp*hdt <= 0.032
        float e3 = y3 - y1;             // |e3| <= tp*dt  <= 0.063

        float sth, cth, s1, c1;
        sincos2(th, y1, sth, cth, s1, c1);   // c1 bit-identical to R3

        float a1  = Fco * c1 - gamma * w - om2 * sth;
        float th2 = th + hdt * w;
        v2f sdA, cdA;
        near2(th2 - th, e2, sdA, cdA);
        float s2 = fmaf(sth, cdA.x, cth * sdA.x);
        float c2 = fmaf(c1, cdA.y, -(s1 * sdA.y));   // cos(y1+e2)

        float w2_ = w + hdt * a1;
        float a2  = Fco * c2 - gamma * w2_ - om2 * s2;
        float th3 = th + hdt * w2_;
        v2f sdB, cdB;
        near2(th3 - th, e3, sdB, cdB);
        float s3 = fmaf(sth, cdB.x, cth * sdB.x);
        float c4 = fmaf(c1, cdB.y, -(s1 * sdB.y));   // cos(y1+e3)

        float w3_ = w + hdt * a2;
        float a3  = Fco * c2 - gamma * w3_ - om2 * s3;
        float th4 = th + dt * w3_;
        float s4  = sin_near(sth, cth, th4 - th);
        float w4_ = w + dt * a3;
        float a4  = Fco * c4 - gamma * w4_ - om2 * s4;

        float ks_th = w  + 2.0f * w2_ + 2.0f * w3_ + w4_;
        float ks_w  = a1 + 2.0f * a2  + 2.0f * a3  + a4;
        th = th + dt6 * ks_th;
        w  = w + dt6 * ks_w;
        return th;
    };

    float4 ob;
    ob.x = th;
    ob.y = step(0);
    ob.z = step(1);
    ob.w = step(2);
    out4[0] = ob;

    for (int c = 1; c < 250; ++c) {
        int k0 = 4 * c - 1;
        ob.x = step(k0);
        ob.y = step(k0 + 1);
        ob.z = step(k0 + 2);
        ob.w = step(k0 + 3);
        out4[c] = ob;
    }
}

extern "C" void kernel_launch(void* const* d_in, const int* in_sizes, int n_in,
                              void* d_out, int out_size, void* d_ws, size_t ws_size,
                              hipStream_t stream) {
    const float* init   = (const float*)d_in[0];
    const float* params = (const float*)d_in[1];
    float* out = (float*)d_out;
    int B = in_sizes[0] / 2;

    int block = 256;
    int grid  = (B + block - 1) / block;
    hipLaunchKernelGGL(pend_kernel, dim3(grid), dim3(block), 0, stream,
                       init, params, out, B);
}

// Round 5
// 154.555 us; speedup vs baseline: 3.6915x; 1.3249x over previous
//
#include <hip/hip_runtime.h>

// PendulumSolver: B=65536 independent driven pendulums, RK4, 999 steps.
// Round 5: hardware v_sin_f32/v_cos_f32 (revolutions input) with an
// argument-magnitude-INDEPENDENT radians->revolutions reduction:
//   n  = rint(x * Chi)            (magic-number rint; Chi = fp32(1/2pi))
//   rv = fma(x,Chi,-n) + x*Clo    (Cody-Waite split: Chi+Clo = 1/2pi to ~2^-47)
// |rv| <= 0.5 + eps, reduction error ~6e-8 rev (~4e-7 rad) regardless of |x|
// -> stays in evaluation-error class; all radian arguments (th, tp*t,
// tp*(t+hdt), tp*(t+dt)) remain bit-identical to rounds 1-4 (absmax frozen at
// 0.0625 across 4 different trig impls -> ulp-class noise invisible).
// Removes: poly sincos cores, quadrant select/sign logic, forcing near2/recons.
// Keeps: stage-sine recons s2/s3/s4 from (sth, cth) (cheaper than direct).

typedef float v2f __attribute__((ext_vector_type(2)));

__device__ __forceinline__ v2f vfma2(v2f a, v2f b, v2f c) {
#if __has_builtin(__builtin_elementwise_fma)
    return __builtin_elementwise_fma(a, b, c);
#else
    v2f r; r.x = fmaf(a.x, b.x, c.x); r.y = fmaf(a.y, b.y, c.y); return r;
#endif
}
__device__ __forceinline__ v2f splat2(float v) { v2f r; r.x = v; r.y = v; return r; }

// Cody-Waite split of 1/(2*pi), folded at compile time.
__device__ __constant__ const double kInv2PiD = 0.15915494309189533577;

__device__ __forceinline__ float hw_sin_rev(float x) {
#if __has_builtin(__builtin_amdgcn_sinf)
    return __builtin_amdgcn_sinf(x);
#else
    return __sinf(x * 6.28318530717958647692f);
#endif
}
__device__ __forceinline__ float hw_cos_rev(float x) {
#if __has_builtin(__builtin_amdgcn_cosf)
    return __builtin_amdgcn_cosf(x);
#else
    return __cosf(x * 6.28318530717958647692f);
#endif
}

// radians -> revolutions in [-0.5, 0.5]; error ~6e-8 rev independent of |x|.
__device__ __forceinline__ v2f to_rev2(v2f x) {
    constexpr float  Chi   = 0.15915494309189533577f;          // fp32(1/2pi)
    constexpr double ChiD  = (double)Chi;
    constexpr float  Clo   = (float)(0.15915494309189533577 - ChiD);
    const float MAGIC = 12582912.0f;                           // 1.5*2^23
    v2f nb = vfma2(x, splat2(Chi), splat2(MAGIC));
    v2f n  = nb - splat2(MAGIC);
    v2f r  = vfma2(x, splat2(Chi), -n);                        // exact prod in fma
    r = vfma2(x, splat2(Clo), r);
    return r;
}

// sin(th + d) from (sin th, cos th); |d| <= ~0.3. Same coeffs as rounds 3-4.
__device__ __forceinline__ float sin_near(float sth, float cth, float d) {
    float d2 = d * d;
    float sdv = d * fmaf(d2, fmaf(d2, 8.33333333e-3f, -1.66666667e-1f), 1.0f);
    float cdv = fmaf(fmaf(fmaf(d2, -1.38888889e-3f, 4.16666667e-2f), d2, -0.5f),
                     d2, 1.0f);
    return fmaf(sth, cdv, cth * sdv);
}

__global__ __launch_bounds__(256) void pend_kernel(
    const float* __restrict__ init,    // (B,2) theta, thdot
    const float* __restrict__ params,  // (B,4) omega, gamma, A, phi
    float* __restrict__ out,           // (B,1000)
    int B)
{
    int b = blockIdx.x * blockDim.x + threadIdx.x;
    if (b >= B) return;

    float th = init[2 * b + 0];
    float w  = init[2 * b + 1];
    const float omega = params[4 * b + 0];
    const float gamma = params[4 * b + 1];
    const float A     = params[4 * b + 2];
    const float phi   = params[4 * b + 3];

    const float dt  = 0.01f;
    const float hdt = 0.5f * dt;
    const float dt6 = dt / 6.0f;
    const float om2 = omega * omega;
    const float Fco = (A * omega) * omega;
    const float tp  = 6.28318530717958647692f * phi;

    float4* out4 = (float4*)(out + (size_t)b * 1000);

    auto step = [&](int k) -> float {
        float t  = (float)k * dt;
        float y1 = tp * t;                       // bit-identical args to R1-R4
        v2f ta; ta.x = t + hdt; ta.y = t + dt;
        v2f y23 = splat2(tp) * ta;               // y2 = tp*(t+hdt), y3 = tp*(t+dt)

        v2f ra; ra.x = th; ra.y = y1;
        v2f rva = to_rev2(ra);
        v2f rvb = to_rev2(y23);

        float sth = hw_sin_rev(rva.x);
        float cth = hw_cos_rev(rva.x);
        float c1  = hw_cos_rev(rva.y);
        float c2  = hw_cos_rev(rvb.x);           // stages 2 and 3 share this
        float c4  = hw_cos_rev(rvb.y);

        float a1  = Fco * c1 - gamma * w - om2 * sth;
        float th2 = th + hdt * w;
        float s2  = sin_near(sth, cth, th2 - th);
        float w2_ = w + hdt * a1;
        float a2  = Fco * c2 - gamma * w2_ - om2 * s2;
        float th3 = th + hdt * w2_;
        float s3  = sin_near(sth, cth, th3 - th);
        float w3_ = w + hdt * a2;
        float a3  = Fco * c2 - gamma * w3_ - om2 * s3;
        float th4 = th + dt * w3_;
        float s4  = sin_near(sth, cth, th4 - th);
        float w4_ = w + dt * a3;
        float a4  = Fco * c4 - gamma * w4_ - om2 * s4;

        float ks_th = w  + 2.0f * w2_ + 2.0f * w3_ + w4_;
        float ks_w  = a1 + 2.0f * a2  + 2.0f * a3  + a4;
        th = th + dt6 * ks_th;
        w  = w + dt6 * ks_w;
        return th;
    };

    float4 ob;
    ob.x = th;
    ob.y = step(0);
    ob.z = step(1);
    ob.w = step(2);
    out4[0] = ob;

    for (int c = 1; c < 250; ++c) {
        int k0 = 4 * c - 1;
        ob.x = step(k0);
        ob.y = step(k0 + 1);
        ob.z = step(k0 + 2);
        ob.w = step(k0 + 3);
        out4[c] = ob;
    }
}

extern "C" void kernel_launch(void* const* d_in, const int* in_sizes, int n_in,
                              void* d_out, int out_size, void* d_ws, size_t ws_size,
                              hipStream_t stream) {
    const float* init   = (const float*)d_in[0];
    const float* params = (const float*)d_in[1];
    float* out = (float*)d_out;
    int B = in_sizes[0] / 2;

    int block = 256;
    int grid  = (B + block - 1) / block;
    hipLaunchKernelGGL(pend_kernel, dim3(grid), dim3(block), 0, stream,
                       init, params, out, B);
}

// Round 6
// 137.464 us; speedup vs baseline: 4.1505x; 1.1243x over previous
//
#include <hip/hip_runtime.h>

// PendulumSolver: B=65536 independent driven pendulums, RK4, 999 steps.
// Round 6: ALL trig via direct HW v_sin/v_cos (revolutions) with CW-split
// radians->revolutions reduction. Drops R3-R5's small-angle recon polys and
// the cos(th) eval entirely: a software recon (10 VALU inst) costs more than
// a direct eval (4-inst reduction + 1 trans op).
// Numerics: every trig ARGUMENT (th, th2, th3, th4, tp*t, tp*(t+hdt),
// tp*(t+dt)) is computed bit-identically to rounds 1-5; reduction error
// ~1.2e-7 rev independent of |x| (Chi+Clo split), same eval class R5 passed
// with (absmax frozen at 0.0625 across 5 impls).

typedef float v2f __attribute__((ext_vector_type(2)));

__device__ __forceinline__ v2f vfma2(v2f a, v2f b, v2f c) {
#if __has_builtin(__builtin_elementwise_fma)
    return __builtin_elementwise_fma(a, b, c);
#else
    v2f r; r.x = fmaf(a.x, b.x, c.x); r.y = fmaf(a.y, b.y, c.y); return r;
#endif
}
__device__ __forceinline__ v2f splat2(float v) { v2f r; r.x = v; r.y = v; return r; }

#define CHI_F 0.15915494309189533577f
#define CLO_F ((float)(0.15915494309189533577 - (double)0.15915494309189533577f))
#define MAGIC_F 12582912.0f   // 1.5 * 2^23

// radians -> revolutions in [-0.5, 0.5]; error ~1.2e-7 rev independent of |x|.
__device__ __forceinline__ v2f to_rev2(v2f x) {
    v2f nb = vfma2(x, splat2(CHI_F), splat2(MAGIC_F));
    v2f n  = nb - splat2(MAGIC_F);
    v2f r  = vfma2(x, splat2(CHI_F), -n);    // product exact inside fma
    r = vfma2(x, splat2(CLO_F), r);
    return r;
}
__device__ __forceinline__ float to_rev1(float x) {
    float nb = fmaf(x, CHI_F, MAGIC_F);
    float n  = nb - MAGIC_F;
    float r  = fmaf(x, CHI_F, -n);
    return fmaf(x, CLO_F, r);
}

__device__ __forceinline__ float hw_sin_rev(float x) {
#if __has_builtin(__builtin_amdgcn_sinf)
    return __builtin_amdgcn_sinf(x);
#else
    return __sinf(x * 6.28318530717958647692f);
#endif
}
__device__ __forceinline__ float hw_cos_rev(float x) {
#if __has_builtin(__builtin_amdgcn_cosf)
    return __builtin_amdgcn_cosf(x);
#else
    return __cosf(x * 6.28318530717958647692f);
#endif
}

__global__ __launch_bounds__(256) void pend_kernel(
    const float* __restrict__ init,    // (B,2) theta, thdot
    const float* __restrict__ params,  // (B,4) omega, gamma, A, phi
    float* __restrict__ out,           // (B,1000)
    int B)
{
    int b = blockIdx.x * blockDim.x + threadIdx.x;
    if (b >= B) return;

    float th = init[2 * b + 0];
    float w  = init[2 * b + 1];
    const float omega = params[4 * b + 0];
    const float gamma = params[4 * b + 1];
    const float A     = params[4 * b + 2];
    const float phi   = params[4 * b + 3];

    const float dt  = 0.01f;
    const float hdt = 0.5f * dt;
    const float dt6 = dt / 6.0f;
    const float om2 = omega * omega;
    const float Fco = (A * omega) * omega;
    const float tp  = 6.28318530717958647692f * phi;

    float4* out4 = (float4*)(out + (size_t)b * 1000);

    // fk tracks (float)k exactly (k < 2^24).
    float fk = 0.0f;

    auto step = [&]() -> float {
        float t  = fk * dt;                 // == (float)k * dt bit-exact
        fk += 1.0f;
        float t2 = t + hdt;
        float t3 = t + dt;
        v2f y12; y12.x = tp * t; y12.y = tp * t2;   // forcing args, bit-exact
        float y3  = tp * t3;
        float th2 = fmaf(hdt, w, th);       // == fl(th + fl(hdt*w)) contracted as R1-R5

        v2f ra; ra.x = th; ra.y = th2;
        v2f rA = to_rev2(ra);
        v2f rB = to_rev2(y12);
        float r3 = to_rev1(y3);

        float sth = hw_sin_rev(rA.x);
        float s2  = hw_sin_rev(rA.y);
        float c1  = hw_cos_rev(rB.x);
        float c2  = hw_cos_rev(rB.y);       // shared by stages 2 and 3
        float c4  = hw_cos_rev(r3);

        float a1  = Fco * c1 - gamma * w   - om2 * sth;
        float w2_ = fmaf(hdt, a1, w);
        float a2  = Fco * c2 - gamma * w2_ - om2 * s2;
        float th3 = fmaf(hdt, w2_, th);
        float s3  = hw_sin_rev(to_rev1(th3));
        float w3_ = fmaf(hdt, a2, w);
        float a3  = Fco * c2 - gamma * w3_ - om2 * s3;
        float th4 = fmaf(dt, w3_, th);
        float s4  = hw_sin_rev(to_rev1(th4));
        float w4_ = fmaf(dt, a3, w);
        float a4  = Fco * c4 - gamma * w4_ - om2 * s4;

        float ks_th = w  + 2.0f * w2_ + 2.0f * w3_ + w4_;
        float ks_w  = a1 + 2.0f * a2  + 2.0f * a3  + a4;
        th = fmaf(dt6, ks_th, th);
        w  = fmaf(dt6, ks_w,  w);
        return th;
    };

    float4 ob;
    ob.x = th;
    ob.y = step();
    ob.z = step();
    ob.w = step();
    out4[0] = ob;

    for (int c = 1; c < 250; ++c) {
        ob.x = step();
        ob.y = step();
        ob.z = step();
        ob.w = step();
        out4[c] = ob;
    }
}

extern "C" void kernel_launch(void* const* d_in, const int* in_sizes, int n_in,
                              void* d_out, int out_size, void* d_ws, size_t ws_size,
                              hipStream_t stream) {
    const float* init   = (const float*)d_in[0];
    const float* params = (const float*)d_in[1];
    float* out = (float*)d_out;
    int B = in_sizes[0] / 2;

    int block = 256;
    int grid  = (B + block - 1) / block;
    hipLaunchKernelGGL(pend_kernel, dim3(grid), dim3(block), 0, stream,
                       init, params, out, B);
}